// Round 12
// baseline (373.661 us; speedup 1.0000x reference)
//
#include <hip/hip_runtime.h>
#include <hip/hip_bf16.h>

typedef __bf16 bf16;
typedef __bf16 bf16x8 __attribute__((ext_vector_type(8)));
typedef float f32x4 __attribute__((ext_vector_type(4)));
typedef unsigned char u8;
typedef unsigned int u32;
typedef unsigned short u16;
typedef u16 ushort4v __attribute__((ext_vector_type(4)));
typedef u32 u32x4 __attribute__((ext_vector_type(4)));

#define B_ 4
#define T_ 1024
#define NX_ 1024
#define NH_ 16
#define HD_ 64

__device__ __forceinline__ void gld16(const void* g, void* l) {
  __builtin_amdgcn_global_load_lds((const __attribute__((address_space(1))) void*)g,
                                   (__attribute__((address_space(3))) void*)l, 16, 0, 0);
}

// ---------- prep: contiguous fp32 -> bf16 ----------
__global__ __launch_bounds__(256) void k_cvt(const float* __restrict__ in, bf16* __restrict__ out, int n) {
  int i = (blockIdx.x * 256 + threadIdx.x) * 4;
  if (i + 3 < n) {
    float4 v = *(const float4*)(in + i);
    out[i] = (bf16)v.x; out[i + 1] = (bf16)v.y; out[i + 2] = (bf16)v.z; out[i + 3] = (bf16)v.w;
  }
}

// ---------- prep: (K,N) f32 -> (N,K) bf16 transpose ----------
__global__ __launch_bounds__(256) void k_transpose(const float* __restrict__ in, bf16* __restrict__ out, int K, int N) {
  __shared__ float tile[64][65];
  int n0 = blockIdx.x * 64, k0 = blockIdx.y * 64;
  for (int i = threadIdx.x; i < 4096; i += 256) {
    int r = i >> 6, c = i & 63;
    tile[r][c] = in[(size_t)(k0 + r) * N + n0 + c];
  }
  __syncthreads();
  for (int i = threadIdx.x; i < 4096; i += 256) {
    int r = i >> 6, c = i & 63;
    out[(size_t)(n0 + r) * K + k0 + c] = (bf16)tile[c][r];
  }
}

// ---------- pack int32 ids -> u8 ([t][s] natural layout; rel 4MB then rel_ids 1MB) ----------
__global__ __launch_bounds__(256) void k_pack(const int* __restrict__ rel, const int* __restrict__ rel_ids,
                                              u8* __restrict__ dst8) {
  int i = (blockIdx.x * 256 + threadIdx.x) * 4;
  const int* src = (i < 4194304) ? (rel + i) : (rel_ids + (i - 4194304));
  int4 v = *(const int4*)src;
  uchar4 o = {(u8)v.x, (u8)v.y, (u8)v.z, (u8)v.w};
  *(uchar4*)(dst8 + i) = o;
}

// ---------- rel_values^T as bf16 (64d x 64rr) for epilogue MFMA ----------
__global__ __launch_bounds__(256) void k_rvt(const float* __restrict__ rel_values, bf16* __restrict__ rvT) {
  int d = threadIdx.x >> 2, seg = threadIdx.x & 3;
  for (int i = 0; i < 16; ++i) {
    int rr = seg * 16 + i;
    rvT[d * 64 + rr] = (bf16)rel_values[rr * 64 + d];
  }
}

// ---------- 128x128 bf16 MFMA GEMM, BK=32, double-buffered global_load_lds ----------
template <int EPI>
__global__ __launch_bounds__(256) void k_gemm(
    const bf16* __restrict__ A, const bf16* __restrict__ BT, const float* __restrict__ bias,
    float* __restrict__ outF, bf16* __restrict__ qg, bf16* __restrict__ kg, bf16* __restrict__ vtg,
    int M, int N, int K) {
  __shared__ __align__(16) bf16 Ab[2][128 * 32];
  __shared__ __align__(16) bf16 Bb[2][128 * 32];
  int tid = threadIdx.x, lane = tid & 63, w = tid >> 6;
  int wm = w >> 1, wn = w & 1;
  int m0 = blockIdx.y * 128, n0 = blockIdx.x * 128;
  int sl = lane >> 4, lr = lane & 15;
  f32x4 acc[4][4] = {};
  int NKt = K >> 5;

  auto stage = [&](int kt, int bidx) {
    const bf16* Ag = A + (size_t)m0 * K + kt * 32;
    const bf16* Bg = BT + (size_t)n0 * K + kt * 32;
#pragma unroll
    for (int j = 0; j < 2; ++j) {
      int c = w * 128 + j * 64 + lane;
      int row = c >> 2, slot = c & 3;
      int ss = slot ^ ((row >> 1) & 3);
      gld16(Ag + (size_t)row * K + ss * 8, &Ab[bidx][(w * 128 + j * 64) * 8]);
      gld16(Bg + (size_t)row * K + ss * 8, &Bb[bidx][(w * 128 + j * 64) * 8]);
    }
  };
  stage(0, 0);
  for (int kt = 0; kt < NKt; ++kt) {
    int bidx = kt & 1;
    __syncthreads();
    if (kt + 1 < NKt) stage(kt + 1, bidx ^ 1);
    bf16x8 af[4], bfv[4];
#pragma unroll
    for (int mi = 0; mi < 4; ++mi) {
      int row = wm * 64 + mi * 16 + lr;
      af[mi] = *(const bf16x8*)&Ab[bidx][row * 32 + ((sl ^ ((row >> 1) & 3)) * 8)];
    }
#pragma unroll
    for (int ni = 0; ni < 4; ++ni) {
      int row = wn * 64 + ni * 16 + lr;
      bfv[ni] = *(const bf16x8*)&Bb[bidx][row * 32 + ((sl ^ ((row >> 1) & 3)) * 8)];
    }
#pragma unroll
    for (int mi = 0; mi < 4; ++mi)
#pragma unroll
      for (int ni = 0; ni < 4; ++ni)
        acc[mi][ni] = __builtin_amdgcn_mfma_f32_16x16x32_bf16(af[mi], bfv[ni], acc[mi][ni], 0, 0, 0);
  }
#pragma unroll
  for (int ni = 0; ni < 4; ++ni) {
    int n = n0 + wn * 64 + ni * 16 + lr;
    float bv = bias[n];
#pragma unroll
    for (int mi = 0; mi < 4; ++mi) {
      int mb = m0 + wm * 64 + mi * 16 + sl * 4;
#pragma unroll
      for (int r = 0; r < 4; ++r) {
        float v = acc[mi][ni][r] + bv;
        int m = mb + r;
        if (EPI == 0) {
          int region = n >> 10, hh = (n & 1023) >> 6, d = n & 63;
          int bb = m >> 10, t = m & 1023;
          int bh = bb * NH_ + hh;
          if (region == 0)      qg[((size_t)bh * T_ + t) * HD_ + d] = (bf16)v;
          else if (region == 1) kg[((size_t)bh * T_ + t) * HD_ + d] = (bf16)v;
          else                  vtg[((size_t)bh * HD_ + d) * T_ + t] = (bf16)v;
        } else {
          outF[(size_t)m * N + n] = v;
        }
      }
    }
  }
}

// ---------- register-staged wave-independent fused attention (named-reg pipeline) ----------
// 1 wave per 16-row Q strip. All staging in explicitly named registers (no aggregates -> no scratch).
// S^T = mfma(K,Q): lane(lr,sl): t=lr, s=si*16+sl*4+r.  O^T = mfma(V^T,P^T): t=lr, d=ni*16+sl*4+r.

#define LOADKV(s0v, k00, k01, k10, k11, v0, v1, v2, v3, rid0, rid1, iid0, iid1)  \
  do {                                                                           \
    int s0_ = (s0v);                                                             \
    k00 = *(const bf16x8*)(klane + (size_t)s0_ * HD_);                           \
    k01 = *(const bf16x8*)(klane + (size_t)s0_ * HD_ + 32);                      \
    k10 = *(const bf16x8*)(klane + (size_t)(s0_ + 16) * HD_);                    \
    k11 = *(const bf16x8*)(klane + (size_t)(s0_ + 16) * HD_ + 32);               \
    v0 = *(const bf16x8*)(vlane + s0_);                                          \
    v1 = *(const bf16x8*)(vlane + 16 * T_ + s0_);                                \
    v2 = *(const bf16x8*)(vlane + 32 * T_ + s0_);                                \
    v3 = *(const bf16x8*)(vlane + 48 * T_ + s0_);                                \
    rid0 = *(const u32*)(ridlane + s0_);                                         \
    rid1 = *(const u32*)(ridlane + s0_ + 16);                                    \
    iid0 = *(const u32*)(iidlane + s0_);                                         \
    iid1 = *(const u32*)(iidlane + s0_ + 16);                                    \
  } while (0)

#define COMPUTE(s0v, k00, k01, k10, k11, v0, v1, v2, v3, rid0, rid1, iid0, iid1) \
  do {                                                                           \
    int s0_ = (s0v);                                                             \
    f32x4 S0_ = {}, S1_ = {};                                                    \
    S0_ = __builtin_amdgcn_mfma_f32_16x16x32_bf16(k00, qf0, S0_, 0, 0, 0);       \
    S0_ = __builtin_amdgcn_mfma_f32_16x16x32_bf16(k01, qf1, S0_, 0, 0, 0);       \
    S1_ = __builtin_amdgcn_mfma_f32_16x16x32_bf16(k10, qf0, S1_, 0, 0, 0);       \
    S1_ = __builtin_amdgcn_mfma_f32_16x16x32_bf16(k11, qf1, S1_, 0, 0, 0);       \
    u16 pb_[8];                                                                  \
    {                                                                            \
      int sbase_ = s0_ + sl * 4;                                                 \
      _Pragma("unroll") for (int r = 0; r < 4; ++r) {                            \
        float e = (sbase_ + r <= tglob)                                          \
                      ? __expf(S0_[r] * 0.125f) * tab[(rid0 >> (8 * r)) & 63]    \
                      : 0.f;                                                     \
        lsum += e;                                                               \
        bf16 eb = (bf16)e;                                                       \
        pb_[r] = *(u16*)&eb;                                                     \
        if (e != 0.f) atomicAdd(&prel[lr * 68 + ((iid0 >> (8 * r)) & 63)], e);   \
      }                                                                          \
      sbase_ += 16;                                                              \
      _Pragma("unroll") for (int r = 0; r < 4; ++r) {                            \
        float e = (sbase_ + r <= tglob)                                          \
                      ? __expf(S1_[r] * 0.125f) * tab[(rid1 >> (8 * r)) & 63]    \
                      : 0.f;                                                     \
        lsum += e;                                                               \
        bf16 eb = (bf16)e;                                                       \
        pb_[4 + r] = *(u16*)&eb;                                                 \
        if (e != 0.f) atomicAdd(&prel[lr * 68 + ((iid1 >> (8 * r)) & 63)], e);   \
      }                                                                          \
    }                                                                            \
    u32 a0_ = (u32)pb_[0] | ((u32)pb_[1] << 16);                                 \
    u32 b0_ = (u32)pb_[2] | ((u32)pb_[3] << 16);                                 \
    u32 a1_ = (u32)pb_[4] | ((u32)pb_[5] << 16);                                 \
    u32 b1_ = (u32)pb_[6] | ((u32)pb_[7] << 16);                                 \
    int srcA_ = lr + (((sl & 1) * 2) << 4);                                      \
    int srcB_ = srcA_ + 16;                                                      \
    u32 taA0_ = (u32)__shfl((int)a0_, srcA_), taA1_ = (u32)__shfl((int)a1_, srcA_); \
    u32 tbA0_ = (u32)__shfl((int)b0_, srcA_), tbA1_ = (u32)__shfl((int)b1_, srcA_); \
    u32 taB0_ = (u32)__shfl((int)a0_, srcB_), taB1_ = (u32)__shfl((int)a1_, srcB_); \
    u32 tbB0_ = (u32)__shfl((int)b0_, srcB_), tbB1_ = (u32)__shfl((int)b1_, srcB_); \
    bool hi_ = (sl & 2) != 0;                                                    \
    u32x4 wv_;                                                                   \
    wv_[0] = hi_ ? taA1_ : taA0_;                                                \
    wv_[1] = hi_ ? tbA1_ : tbA0_;                                                \
    wv_[2] = hi_ ? taB1_ : taB0_;                                                \
    wv_[3] = hi_ ? tbB1_ : tbB0_;                                                \
    bf16x8 pfrag_ = *(bf16x8*)&wv_;                                              \
    acc[0] = __builtin_amdgcn_mfma_f32_16x16x32_bf16(v0, pfrag_, acc[0], 0, 0, 0); \
    acc[1] = __builtin_amdgcn_mfma_f32_16x16x32_bf16(v1, pfrag_, acc[1], 0, 0, 0); \
    acc[2] = __builtin_amdgcn_mfma_f32_16x16x32_bf16(v2, pfrag_, acc[2], 0, 0, 0); \
    acc[3] = __builtin_amdgcn_mfma_f32_16x16x32_bf16(v3, pfrag_, acc[3], 0, 0, 0); \
  } while (0)

__global__ __launch_bounds__(64, 3) void k_attn(
    const bf16* __restrict__ qg, const bf16* __restrict__ kg, const bf16* __restrict__ vtg,
    const u8* __restrict__ rel8, const float* __restrict__ rel_weights,
    const u8* __restrict__ relid8, const bf16* __restrict__ rvT,
    bf16* __restrict__ ret) {
  __shared__ float prel[16 * 68];   // [16t][64+4pad] buckets
  __shared__ float tab[64];

  int bx = blockIdx.x;
  int tt = 63 - (bx & 63);          // heavy strips first
  int h = (bx >> 6) & 15, b = bx >> 10;
  int bh = b * NH_ + h;
  int t0 = tt * 16;
  int lane = threadIdx.x;
  int lr = lane & 15, sl = lane >> 4;

  tab[lane] = __expf(rel_weights[lane * NH_ + h]);
#pragma unroll
  for (int i = 0; i < 17; ++i) prel[i * 64 + lane] = 0.f;

  // Q B-frag: lane(lr,sl) holds Q[t=t0+lr][d = (qf0: sl*8..) (qf1: 32+sl*8..)]
  const bf16* qrow = qg + ((size_t)bh * T_ + t0 + lr) * HD_;
  bf16x8 qf0 = *(const bf16x8*)(qrow + sl * 8);
  bf16x8 qf1 = *(const bf16x8*)(qrow + 32 + sl * 8);

  // per-lane base pointers
  const bf16* klane = kg + ((size_t)bh * T_ + lr) * HD_ + sl * 8;
  const bf16* vlane = vtg + ((size_t)bh * HD_ + lr) * T_ + sl * 8;
  const u8* ridlane = rel8 + (size_t)b * T_ * T_ + (size_t)(t0 + lr) * T_ + sl * 4;
  const u8* iidlane = relid8 + (size_t)(t0 + lr) * T_ + sl * 4;

  f32x4 acc[4] = {};
  float lsum = 0.f;
  int tglob = t0 + lr;

  // named ping-pong registers (no aggregates -> stays in VGPRs)
  bf16x8 ak00, ak01, ak10, ak11, av0, av1, av2, av3;
  u32 arid0, arid1, aiid0, aiid1;
  bf16x8 bk00, bk01, bk10, bk11, bv0, bv1, bv2, bv3;
  u32 brid0, brid1, biid0, biid1;

  int nst = (tt >> 1) + 1;
  LOADKV(0, ak00, ak01, ak10, ak11, av0, av1, av2, av3, arid0, arid1, aiid0, aiid1);
  for (int st = 0; st < nst; st += 2) {
    if (st + 1 < nst)
      LOADKV((st + 1) * 32, bk00, bk01, bk10, bk11, bv0, bv1, bv2, bv3, brid0, brid1, biid0, biid1);
    COMPUTE(st * 32, ak00, ak01, ak10, ak11, av0, av1, av2, av3, arid0, arid1, aiid0, aiid1);
    if (st + 1 < nst) {
      if (st + 2 < nst)
        LOADKV((st + 2) * 32, ak00, ak01, ak10, ak11, av0, av1, av2, av3, arid0, arid1, aiid0, aiid1);
      COMPUTE((st + 1) * 32, bk00, bk01, bk10, bk11, bv0, bv1, bv2, bv3, brid0, brid1, biid0, biid1);
    }
  }

  // ---- epilogue ----
  float v = lsum;
  v += __shfl_xor(v, 16);
  v += __shfl_xor(v, 32);
  float inv = 1.f / v;                 // per-lane, t = lr (uniform across sl)

  // rel-values term via MFMA: acc[ni] += rvT_frag x prel^T_frag
  asm volatile("s_waitcnt lgkmcnt(0)" ::: "memory");
  __builtin_amdgcn_sched_barrier(0);
#pragma unroll
  for (int kc = 0; kc < 2; ++kc) {
    f32x4 pA = *(const f32x4*)&prel[lr * 68 + kc * 32 + sl * 8];
    f32x4 pB = *(const f32x4*)&prel[lr * 68 + kc * 32 + sl * 8 + 4];
    u16 pb[8];
#pragma unroll
    for (int j = 0; j < 4; ++j) { bf16 x = (bf16)pA[j]; pb[j] = *(u16*)&x; }
#pragma unroll
    for (int j = 0; j < 4; ++j) { bf16 x = (bf16)pB[j]; pb[4 + j] = *(u16*)&x; }
    bf16x8 pfrag = *(bf16x8*)&pb[0];
#pragma unroll
    for (int ni = 0; ni < 4; ++ni) {
      bf16x8 af = *(const bf16x8*)(rvT + (size_t)(ni * 16 + lr) * 64 + kc * 32 + sl * 8);
      acc[ni] = __builtin_amdgcn_mfma_f32_16x16x32_bf16(af, pfrag, acc[ni], 0, 0, 0);
    }
  }

  // normalize + store: lane(lr,sl) owns t=t0+lr, d = ni*16 + sl*4 .. +4
  bf16* rp = ret + ((size_t)(b * T_ + t0 + lr)) * NX_ + h * HD_ + sl * 4;
#pragma unroll
  for (int ni = 0; ni < 4; ++ni) {
    ushort4v ov;
#pragma unroll
    for (int r = 0; r < 4; ++r) {
      bf16 x = (bf16)(acc[ni][r] * inv);
      ov[r] = *(u16*)&x;
    }
    *(ushort4v*)(rp + ni * 16) = ov;
  }
}

extern "C" void kernel_launch(void* const* d_in, const int* in_sizes, int n_in,
                              void* d_out, int out_size, void* d_ws, size_t ws_size,
                              hipStream_t stream) {
  const float* x = (const float*)d_in[0];
  const int* rel = (const int*)d_in[1];
  const float* w_attn = (const float*)d_in[2];
  const float* b_attn = (const float*)d_in[3];
  const float* w_proj = (const float*)d_in[4];
  const float* b_proj = (const float*)d_in[5];
  const float* rel_weights = (const float*)d_in[6];
  const float* rel_values = (const float*)d_in[7];
  const int* rel_ids = (const int*)d_in[8];
  float* out = (float*)d_out;

  char* ws = (char*)d_ws;
  bf16* xb  = (bf16*)(ws);                    //  8 MB: x as bf16 (consumed by gemm<0>)
  bf16* wTa = (bf16*)(ws + 8388608);          //  6 MB: w_attn^T
  bf16* wTp = (bf16*)(ws + 14680064);         //  2 MB: w_proj^T
  bf16* qg  = (bf16*)(ws + 16777216);         //  8 MB: q (bh,t,d)
  bf16* kg  = (bf16*)(ws + 25165824);         //  8 MB: k (bh,t,d)
  bf16* vtg = (bf16*)(ws + 33554432);         //  8 MB: v^T (bh,d,t)
  bf16* ret = (bf16*)(ws + 41943040);         //  8 MB: attn out (b,t,nx)
  // overlays on dead xb region (after gemm<0> consumed it):
  u8* rel8   = (u8*)(ws);                     //  4 MB: rel ids u8 [b][t][s]
  u8* relid8 = (u8*)(ws + 4194304);           //  1 MB: rel_ids u8 [t][s]
  bf16* rvT  = (bf16*)(ws + 5242880);         //  8 KB: rel_values^T bf16 (64d x 64rr)

  k_cvt<<<4096, 256, 0, stream>>>(x, xb, 4194304);
  k_transpose<<<dim3(48, 16), 256, 0, stream>>>(w_attn, wTa, 1024, 3072);
  k_transpose<<<dim3(16, 16), 256, 0, stream>>>(w_proj, wTp, 1024, 1024);
  k_gemm<0><<<dim3(24, 32), 256, 0, stream>>>(xb, wTa, b_attn, nullptr, qg, kg, vtg, 4096, 3072, 1024);
  k_pack<<<5120, 256, 0, stream>>>(rel, rel_ids, rel8);
  k_rvt<<<1, 256, 0, stream>>>(rel_values, rvT);
  k_attn<<<4096, 64, 0, stream>>>(qg, kg, vtg, rel8, rel_weights, relid8, rvT, ret);
  k_gemm<1><<<dim3(8, 32), 256, 0, stream>>>(ret, wTp, b_proj, out, nullptr, nullptr, nullptr, 4096, 1024, 1024);
}

// Round 13
// 274.009 us; speedup vs baseline: 1.3637x; 1.3637x over previous
//
#include <hip/hip_runtime.h>
#include <hip/hip_bf16.h>

typedef __bf16 bf16;
typedef __bf16 bf16x8 __attribute__((ext_vector_type(8)));
typedef float f32x4 __attribute__((ext_vector_type(4)));
typedef unsigned char u8;
typedef unsigned int u32;
typedef unsigned short u16;
typedef u16 ushort4v __attribute__((ext_vector_type(4)));
typedef u32 u32x4 __attribute__((ext_vector_type(4)));

#define B_ 4
#define T_ 1024
#define NX_ 1024
#define NH_ 16
#define HD_ 64

__device__ __forceinline__ void gld16(const void* g, void* l) {
  __builtin_amdgcn_global_load_lds((const __attribute__((address_space(1))) void*)g,
                                   (__attribute__((address_space(3))) void*)l, 16, 0, 0);
}

// ---------- prep: contiguous fp32 -> bf16 ----------
__global__ __launch_bounds__(256) void k_cvt(const float* __restrict__ in, bf16* __restrict__ out, int n) {
  int i = (blockIdx.x * 256 + threadIdx.x) * 4;
  if (i + 3 < n) {
    float4 v = *(const float4*)(in + i);
    out[i] = (bf16)v.x; out[i + 1] = (bf16)v.y; out[i + 2] = (bf16)v.z; out[i + 3] = (bf16)v.w;
  }
}

// ---------- prep: (K,N) f32 -> (N,K) bf16 transpose ----------
__global__ __launch_bounds__(256) void k_transpose(const float* __restrict__ in, bf16* __restrict__ out, int K, int N) {
  __shared__ float tile[64][65];
  int n0 = blockIdx.x * 64, k0 = blockIdx.y * 64;
  for (int i = threadIdx.x; i < 4096; i += 256) {
    int r = i >> 6, c = i & 63;
    tile[r][c] = in[(size_t)(k0 + r) * N + n0 + c];
  }
  __syncthreads();
  for (int i = threadIdx.x; i < 4096; i += 256) {
    int r = i >> 6, c = i & 63;
    out[(size_t)(n0 + r) * K + k0 + c] = (bf16)tile[c][r];
  }
}

// ---------- pack int32 ids -> u8 ([t][s] natural layout; rel 4MB then rel_ids 1MB) ----------
__global__ __launch_bounds__(256) void k_pack(const int* __restrict__ rel, const int* __restrict__ rel_ids,
                                              u8* __restrict__ dst8) {
  int i = (blockIdx.x * 256 + threadIdx.x) * 4;
  const int* src = (i < 4194304) ? (rel + i) : (rel_ids + (i - 4194304));
  int4 v = *(const int4*)src;
  uchar4 o = {(u8)v.x, (u8)v.y, (u8)v.z, (u8)v.w};
  *(uchar4*)(dst8 + i) = o;
}

// ---------- rel_values^T as bf16 (64d x 64rr) for epilogue MFMA ----------
__global__ __launch_bounds__(256) void k_rvt(const float* __restrict__ rel_values, bf16* __restrict__ rvT) {
  int d = threadIdx.x >> 2, seg = threadIdx.x & 3;
  for (int i = 0; i < 16; ++i) {
    int rr = seg * 16 + i;
    rvT[d * 64 + rr] = (bf16)rel_values[rr * 64 + d];
  }
}

// ---------- 128x128 bf16 MFMA GEMM, BK=32, double-buffered global_load_lds ----------
template <int EPI>
__global__ __launch_bounds__(256) void k_gemm(
    const bf16* __restrict__ A, const bf16* __restrict__ BT, const float* __restrict__ bias,
    float* __restrict__ outF, bf16* __restrict__ qg, bf16* __restrict__ kg, bf16* __restrict__ vtg,
    int M, int N, int K) {
  __shared__ __align__(16) bf16 Ab[2][128 * 32];
  __shared__ __align__(16) bf16 Bb[2][128 * 32];
  int tid = threadIdx.x, lane = tid & 63, w = tid >> 6;
  int wm = w >> 1, wn = w & 1;
  int m0 = blockIdx.y * 128, n0 = blockIdx.x * 128;
  int sl = lane >> 4, lr = lane & 15;
  f32x4 acc[4][4] = {};
  int NKt = K >> 5;

  auto stage = [&](int kt, int bidx) {
    const bf16* Ag = A + (size_t)m0 * K + kt * 32;
    const bf16* Bg = BT + (size_t)n0 * K + kt * 32;
#pragma unroll
    for (int j = 0; j < 2; ++j) {
      int c = w * 128 + j * 64 + lane;
      int row = c >> 2, slot = c & 3;
      int ss = slot ^ ((row >> 1) & 3);
      gld16(Ag + (size_t)row * K + ss * 8, &Ab[bidx][(w * 128 + j * 64) * 8]);
      gld16(Bg + (size_t)row * K + ss * 8, &Bb[bidx][(w * 128 + j * 64) * 8]);
    }
  };
  stage(0, 0);
  for (int kt = 0; kt < NKt; ++kt) {
    int bidx = kt & 1;
    __syncthreads();
    if (kt + 1 < NKt) stage(kt + 1, bidx ^ 1);
    bf16x8 af[4], bfv[4];
#pragma unroll
    for (int mi = 0; mi < 4; ++mi) {
      int row = wm * 64 + mi * 16 + lr;
      af[mi] = *(const bf16x8*)&Ab[bidx][row * 32 + ((sl ^ ((row >> 1) & 3)) * 8)];
    }
#pragma unroll
    for (int ni = 0; ni < 4; ++ni) {
      int row = wn * 64 + ni * 16 + lr;
      bfv[ni] = *(const bf16x8*)&Bb[bidx][row * 32 + ((sl ^ ((row >> 1) & 3)) * 8)];
    }
#pragma unroll
    for (int mi = 0; mi < 4; ++mi)
#pragma unroll
      for (int ni = 0; ni < 4; ++ni)
        acc[mi][ni] = __builtin_amdgcn_mfma_f32_16x16x32_bf16(af[mi], bfv[ni], acc[mi][ni], 0, 0, 0);
  }
#pragma unroll
  for (int ni = 0; ni < 4; ++ni) {
    int n = n0 + wn * 64 + ni * 16 + lr;
    float bv = bias[n];
#pragma unroll
    for (int mi = 0; mi < 4; ++mi) {
      int mb = m0 + wm * 64 + mi * 16 + sl * 4;
#pragma unroll
      for (int r = 0; r < 4; ++r) {
        float v = acc[mi][ni][r] + bv;
        int m = mb + r;
        if (EPI == 0) {
          int region = n >> 10, hh = (n & 1023) >> 6, d = n & 63;
          int bb = m >> 10, t = m & 1023;
          int bh = bb * NH_ + hh;
          if (region == 0)      qg[((size_t)bh * T_ + t) * HD_ + d] = (bf16)v;
          else if (region == 1) kg[((size_t)bh * T_ + t) * HD_ + d] = (bf16)v;
          else                  vtg[((size_t)bh * HD_ + d) * T_ + t] = (bf16)v;
        } else {
          outF[(size_t)m * N + n] = v;
        }
      }
    }
  }
}

// ---------- wave-paired fused attention: 4 waves/block, each wave = heavy+light strip pair ----------
// Equal work per wave (~33 s-tiles). XCD-chunked bid remap for L2 locality.
// Per-strip math identical to validated R12 kernel; prel is per-wave (no cross-wave sync).

#define LOADKV(s0v, k00, k01, k10, k11, v0, v1, v2, v3, rid0, rid1, iid0, iid1)  \
  do {                                                                           \
    int s0_ = (s0v);                                                             \
    k00 = *(const bf16x8*)(klane + (size_t)s0_ * HD_);                           \
    k01 = *(const bf16x8*)(klane + (size_t)s0_ * HD_ + 32);                      \
    k10 = *(const bf16x8*)(klane + (size_t)(s0_ + 16) * HD_);                    \
    k11 = *(const bf16x8*)(klane + (size_t)(s0_ + 16) * HD_ + 32);               \
    v0 = *(const bf16x8*)(vlane + s0_);                                          \
    v1 = *(const bf16x8*)(vlane + 16 * T_ + s0_);                                \
    v2 = *(const bf16x8*)(vlane + 32 * T_ + s0_);                                \
    v3 = *(const bf16x8*)(vlane + 48 * T_ + s0_);                                \
    rid0 = *(const u32*)(ridlane + s0_);                                         \
    rid1 = *(const u32*)(ridlane + s0_ + 16);                                    \
    iid0 = *(const u32*)(iidlane + s0_);                                         \
    iid1 = *(const u32*)(iidlane + s0_ + 16);                                    \
  } while (0)

#define COMPUTE(s0v, k00, k01, k10, k11, v0, v1, v2, v3, rid0, rid1, iid0, iid1) \
  do {                                                                           \
    int s0_ = (s0v);                                                             \
    f32x4 S0_ = {}, S1_ = {};                                                    \
    S0_ = __builtin_amdgcn_mfma_f32_16x16x32_bf16(k00, qf0, S0_, 0, 0, 0);       \
    S0_ = __builtin_amdgcn_mfma_f32_16x16x32_bf16(k01, qf1, S0_, 0, 0, 0);       \
    S1_ = __builtin_amdgcn_mfma_f32_16x16x32_bf16(k10, qf0, S1_, 0, 0, 0);       \
    S1_ = __builtin_amdgcn_mfma_f32_16x16x32_bf16(k11, qf1, S1_, 0, 0, 0);       \
    u16 pb_[8];                                                                  \
    {                                                                            \
      int sbase_ = s0_ + sl * 4;                                                 \
      _Pragma("unroll") for (int r = 0; r < 4; ++r) {                            \
        float e = (sbase_ + r <= tglob)                                          \
                      ? __expf(S0_[r] * 0.125f) * tab[(rid0 >> (8 * r)) & 63]    \
                      : 0.f;                                                     \
        lsum += e;                                                               \
        bf16 eb = (bf16)e;                                                       \
        pb_[r] = *(u16*)&eb;                                                     \
        if (e != 0.f) atomicAdd(&prel[lr * 68 + ((iid0 >> (8 * r)) & 63)], e);   \
      }                                                                          \
      sbase_ += 16;                                                              \
      _Pragma("unroll") for (int r = 0; r < 4; ++r) {                            \
        float e = (sbase_ + r <= tglob)                                          \
                      ? __expf(S1_[r] * 0.125f) * tab[(rid1 >> (8 * r)) & 63]    \
                      : 0.f;                                                     \
        lsum += e;                                                               \
        bf16 eb = (bf16)e;                                                       \
        pb_[4 + r] = *(u16*)&eb;                                                 \
        if (e != 0.f) atomicAdd(&prel[lr * 68 + ((iid1 >> (8 * r)) & 63)], e);   \
      }                                                                          \
    }                                                                            \
    u32 a0_ = (u32)pb_[0] | ((u32)pb_[1] << 16);                                 \
    u32 b0_ = (u32)pb_[2] | ((u32)pb_[3] << 16);                                 \
    u32 a1_ = (u32)pb_[4] | ((u32)pb_[5] << 16);                                 \
    u32 b1_ = (u32)pb_[6] | ((u32)pb_[7] << 16);                                 \
    int srcA_ = lr + (((sl & 1) * 2) << 4);                                      \
    int srcB_ = srcA_ + 16;                                                      \
    u32 taA0_ = (u32)__shfl((int)a0_, srcA_), taA1_ = (u32)__shfl((int)a1_, srcA_); \
    u32 tbA0_ = (u32)__shfl((int)b0_, srcA_), tbA1_ = (u32)__shfl((int)b1_, srcA_); \
    u32 taB0_ = (u32)__shfl((int)a0_, srcB_), taB1_ = (u32)__shfl((int)a1_, srcB_); \
    u32 tbB0_ = (u32)__shfl((int)b0_, srcB_), tbB1_ = (u32)__shfl((int)b1_, srcB_); \
    bool hi_ = (sl & 2) != 0;                                                    \
    u32x4 wv_;                                                                   \
    wv_[0] = hi_ ? taA1_ : taA0_;                                                \
    wv_[1] = hi_ ? tbA1_ : tbA0_;                                                \
    wv_[2] = hi_ ? taB1_ : taB0_;                                                \
    wv_[3] = hi_ ? tbB1_ : tbB0_;                                                \
    bf16x8 pfrag_ = *(bf16x8*)&wv_;                                              \
    acc[0] = __builtin_amdgcn_mfma_f32_16x16x32_bf16(v0, pfrag_, acc[0], 0, 0, 0); \
    acc[1] = __builtin_amdgcn_mfma_f32_16x16x32_bf16(v1, pfrag_, acc[1], 0, 0, 0); \
    acc[2] = __builtin_amdgcn_mfma_f32_16x16x32_bf16(v2, pfrag_, acc[2], 0, 0, 0); \
    acc[3] = __builtin_amdgcn_mfma_f32_16x16x32_bf16(v3, pfrag_, acc[3], 0, 0, 0); \
  } while (0)

__global__ __launch_bounds__(256, 2) void k_attn(
    const bf16* __restrict__ qg, const bf16* __restrict__ kg, const bf16* __restrict__ vtg,
    const u8* __restrict__ rel8, const float* __restrict__ rel_weights,
    const u8* __restrict__ relid8, const bf16* __restrict__ rvT,
    bf16* __restrict__ ret) {
  __shared__ float prelBase[4 * 1088];   // per-wave [16t][64+4pad]
  __shared__ float tabBase[4 * 64];      // per-wave exp(rel_weights[:,h])

  // XCD-chunked decode: xcd = bid&7 (round-robin assumption, perf-only).
  // All 8 blocks of a (b,h) group share one XCD; batch b spans 2 XCDs.
  int bid = blockIdx.x;
  int x = bid & 7, j = bid >> 3;
  int b = x >> 1;
  int h = (x & 1) + ((j >> 3) << 1);
  int q = j & 7;
  int w = threadIdx.x >> 6;
  int lane = threadIdx.x & 63;
  int lr = lane & 15, sl = lane >> 4;
  int p = q * 4 + w;                     // pair index in [0,32)
  int bh = b * NH_ + h;

  float* prel = prelBase + w * 1088;
  float* tab = tabBase + w * 64;
  tab[lane] = __expf(rel_weights[lane * NH_ + h]);

  const u8* relbase = rel8 + (size_t)b * T_ * T_;

#pragma unroll
  for (int side = 0; side < 2; ++side) {
    int tt = side ? p : 63 - p;          // heavy strip first
    int t0 = tt * 16;
    int tglob = t0 + lr;

#pragma unroll
    for (int i = 0; i < 17; ++i) prel[i * 64 + lane] = 0.f;

    const bf16* qrow = qg + ((size_t)bh * T_ + t0 + lr) * HD_;
    bf16x8 qf0 = *(const bf16x8*)(qrow + sl * 8);
    bf16x8 qf1 = *(const bf16x8*)(qrow + 32 + sl * 8);

    const bf16* klane = kg + ((size_t)bh * T_ + lr) * HD_ + sl * 8;
    const bf16* vlane = vtg + ((size_t)bh * HD_ + lr) * T_ + sl * 8;
    const u8* ridlane = relbase + (size_t)(t0 + lr) * T_ + sl * 4;
    const u8* iidlane = relid8 + (size_t)(t0 + lr) * T_ + sl * 4;

    f32x4 acc[4] = {};
    float lsum = 0.f;

    bf16x8 ak00, ak01, ak10, ak11, av0, av1, av2, av3;
    u32 arid0, arid1, aiid0, aiid1;
    bf16x8 bk00, bk01, bk10, bk11, bv0, bv1, bv2, bv3;
    u32 brid0, brid1, biid0, biid1;

    int nst = (tt >> 1) + 1;
    LOADKV(0, ak00, ak01, ak10, ak11, av0, av1, av2, av3, arid0, arid1, aiid0, aiid1);
    for (int st = 0; st < nst; st += 2) {
      if (st + 1 < nst)
        LOADKV((st + 1) * 32, bk00, bk01, bk10, bk11, bv0, bv1, bv2, bv3, brid0, brid1, biid0, biid1);
      COMPUTE(st * 32, ak00, ak01, ak10, ak11, av0, av1, av2, av3, arid0, arid1, aiid0, aiid1);
      if (st + 1 < nst) {
        if (st + 2 < nst)
          LOADKV((st + 2) * 32, ak00, ak01, ak10, ak11, av0, av1, av2, av3, arid0, arid1, aiid0, aiid1);
        COMPUTE((st + 1) * 32, bk00, bk01, bk10, bk11, bv0, bv1, bv2, bv3, brid0, brid1, biid0, biid1);
      }
    }

    // ---- per-strip epilogue ----
    float v = lsum;
    v += __shfl_xor(v, 16);
    v += __shfl_xor(v, 32);
    float inv = 1.f / v;

    asm volatile("s_waitcnt lgkmcnt(0)" ::: "memory");
    __builtin_amdgcn_sched_barrier(0);
#pragma unroll
    for (int kc = 0; kc < 2; ++kc) {
      f32x4 pA = *(const f32x4*)&prel[lr * 68 + kc * 32 + sl * 8];
      f32x4 pB = *(const f32x4*)&prel[lr * 68 + kc * 32 + sl * 8 + 4];
      u16 pb[8];
#pragma unroll
      for (int jj = 0; jj < 4; ++jj) { bf16 xx = (bf16)pA[jj]; pb[jj] = *(u16*)&xx; }
#pragma unroll
      for (int jj = 0; jj < 4; ++jj) { bf16 xx = (bf16)pB[jj]; pb[4 + jj] = *(u16*)&xx; }
      bf16x8 pfrag = *(bf16x8*)&pb[0];
#pragma unroll
      for (int ni = 0; ni < 4; ++ni) {
        bf16x8 af = *(const bf16x8*)(rvT + (size_t)(ni * 16 + lr) * 64 + kc * 32 + sl * 8);
        acc[ni] = __builtin_amdgcn_mfma_f32_16x16x32_bf16(af, pfrag, acc[ni], 0, 0, 0);
      }
    }

    bf16* rp = ret + ((size_t)(b * T_ + t0 + lr)) * NX_ + h * HD_ + sl * 4;
#pragma unroll
    for (int ni = 0; ni < 4; ++ni) {
      ushort4v ov;
#pragma unroll
      for (int r = 0; r < 4; ++r) {
        bf16 xx = (bf16)(acc[ni][r] * inv);
        ov[r] = *(u16*)&xx;
      }
      *(ushort4v*)(rp + ni * 16) = ov;
    }
    // prel re-zeroed at top of next side; ds ops complete in-order per wave.
    asm volatile("s_waitcnt lgkmcnt(0)" ::: "memory");
  }
}

extern "C" void kernel_launch(void* const* d_in, const int* in_sizes, int n_in,
                              void* d_out, int out_size, void* d_ws, size_t ws_size,
                              hipStream_t stream) {
  const float* x = (const float*)d_in[0];
  const int* rel = (const int*)d_in[1];
  const float* w_attn = (const float*)d_in[2];
  const float* b_attn = (const float*)d_in[3];
  const float* w_proj = (const float*)d_in[4];
  const float* b_proj = (const float*)d_in[5];
  const float* rel_weights = (const float*)d_in[6];
  const float* rel_values = (const float*)d_in[7];
  const int* rel_ids = (const int*)d_in[8];
  float* out = (float*)d_out;

  char* ws = (char*)d_ws;
  bf16* xb  = (bf16*)(ws);                    //  8 MB: x as bf16 (consumed by gemm<0>)
  bf16* wTa = (bf16*)(ws + 8388608);          //  6 MB: w_attn^T
  bf16* wTp = (bf16*)(ws + 14680064);         //  2 MB: w_proj^T
  bf16* qg  = (bf16*)(ws + 16777216);         //  8 MB: q (bh,t,d)
  bf16* kg  = (bf16*)(ws + 25165824);         //  8 MB: k (bh,t,d)
  bf16* vtg = (bf16*)(ws + 33554432);         //  8 MB: v^T (bh,d,t)
  bf16* ret = (bf16*)(ws + 41943040);         //  8 MB: attn out (b,t,nx)
  // overlays on dead xb region (after gemm<0> consumed it):
  u8* rel8   = (u8*)(ws);                     //  4 MB: rel ids u8 [b][t][s]
  u8* relid8 = (u8*)(ws + 4194304);           //  1 MB: rel_ids u8 [t][s]
  bf16* rvT  = (bf16*)(ws + 5242880);         //  8 KB: rel_values^T bf16 (64d x 64rr)

  k_cvt<<<4096, 256, 0, stream>>>(x, xb, 4194304);
  k_transpose<<<dim3(48, 16), 256, 0, stream>>>(w_attn, wTa, 1024, 3072);
  k_transpose<<<dim3(16, 16), 256, 0, stream>>>(w_proj, wTp, 1024, 1024);
  k_gemm<0><<<dim3(24, 32), 256, 0, stream>>>(xb, wTa, b_attn, nullptr, qg, kg, vtg, 4096, 3072, 1024);
  k_pack<<<5120, 256, 0, stream>>>(rel, rel_ids, rel8);
  k_rvt<<<1, 256, 0, stream>>>(rel_values, rvT);
  k_attn<<<512, 256, 0, stream>>>(qg, kg, vtg, rel8, rel_weights, relid8, rvT, ret);
  k_gemm<1><<<dim3(8, 32), 256, 0, stream>>>(ret, wTp, b_proj, out, nullptr, nullptr, nullptr, 4096, 1024, 1024);
}

// Round 15
// 273.373 us; speedup vs baseline: 1.3669x; 1.0023x over previous
//
#include <hip/hip_runtime.h>
#include <hip/hip_bf16.h>

typedef __bf16 bf16;
typedef __bf16 bf16x8 __attribute__((ext_vector_type(8)));
typedef float f32x4 __attribute__((ext_vector_type(4)));
typedef unsigned char u8;
typedef unsigned int u32;
typedef unsigned short u16;
typedef u16 ushort4v __attribute__((ext_vector_type(4)));
typedef u32 u32x4 __attribute__((ext_vector_type(4)));

#define B_ 4
#define T_ 1024
#define NX_ 1024
#define NH_ 16
#define HD_ 64

__device__ __forceinline__ void gld16(const void* g, void* l) {
  __builtin_amdgcn_global_load_lds((const __attribute__((address_space(1))) void*)g,
                                   (__attribute__((address_space(3))) void*)l, 16, 0, 0);
}

// ---------- prep: contiguous fp32 -> bf16 ----------
__global__ __launch_bounds__(256) void k_cvt(const float* __restrict__ in, bf16* __restrict__ out, int n) {
  int i = (blockIdx.x * 256 + threadIdx.x) * 4;
  if (i + 3 < n) {
    float4 v = *(const float4*)(in + i);
    out[i] = (bf16)v.x; out[i + 1] = (bf16)v.y; out[i + 2] = (bf16)v.z; out[i + 3] = (bf16)v.w;
  }
}

// ---------- prep: (K,N) f32 -> (N,K) bf16 transpose ----------
__global__ __launch_bounds__(256) void k_transpose(const float* __restrict__ in, bf16* __restrict__ out, int K, int N) {
  __shared__ float tile[64][65];
  int n0 = blockIdx.x * 64, k0 = blockIdx.y * 64;
  for (int i = threadIdx.x; i < 4096; i += 256) {
    int r = i >> 6, c = i & 63;
    tile[r][c] = in[(size_t)(k0 + r) * N + n0 + c];
  }
  __syncthreads();
  for (int i = threadIdx.x; i < 4096; i += 256) {
    int r = i >> 6, c = i & 63;
    out[(size_t)(n0 + r) * K + k0 + c] = (bf16)tile[c][r];
  }
}

// ---------- pack int32 ids -> u8 ([t][s] natural layout; rel 4MB then rel_ids 1MB) ----------
__global__ __launch_bounds__(256) void k_pack(const int* __restrict__ rel, const int* __restrict__ rel_ids,
                                              u8* __restrict__ dst8) {
  int i = (blockIdx.x * 256 + threadIdx.x) * 4;
  const int* src = (i < 4194304) ? (rel + i) : (rel_ids + (i - 4194304));
  int4 v = *(const int4*)src;
  uchar4 o = {(u8)v.x, (u8)v.y, (u8)v.z, (u8)v.w};
  *(uchar4*)(dst8 + i) = o;
}

// ---------- rel_values^T as bf16 (64d x 64rr) for epilogue MFMA ----------
__global__ __launch_bounds__(256) void k_rvt(const float* __restrict__ rel_values, bf16* __restrict__ rvT) {
  int d = threadIdx.x >> 2, seg = threadIdx.x & 3;
  for (int i = 0; i < 16; ++i) {
    int rr = seg * 16 + i;
    rvT[d * 64 + rr] = (bf16)rel_values[rr * 64 + d];
  }
}

// ---------- 128x128 bf16 MFMA GEMM, BK=32, double-buffered global_load_lds ----------
template <int EPI>
__global__ __launch_bounds__(256) void k_gemm(
    const bf16* __restrict__ A, const bf16* __restrict__ BT, const float* __restrict__ bias,
    float* __restrict__ outF, bf16* __restrict__ qg, bf16* __restrict__ kg, bf16* __restrict__ vtg,
    int M, int N, int K) {
  __shared__ __align__(16) bf16 Ab[2][128 * 32];
  __shared__ __align__(16) bf16 Bb[2][128 * 32];
  int tid = threadIdx.x, lane = tid & 63, w = tid >> 6;
  int wm = w >> 1, wn = w & 1;
  int m0 = blockIdx.y * 128, n0 = blockIdx.x * 128;
  int sl = lane >> 4, lr = lane & 15;
  f32x4 acc[4][4] = {};
  int NKt = K >> 5;

  auto stage = [&](int kt, int bidx) {
    const bf16* Ag = A + (size_t)m0 * K + kt * 32;
    const bf16* Bg = BT + (size_t)n0 * K + kt * 32;
#pragma unroll
    for (int j = 0; j < 2; ++j) {
      int c = w * 128 + j * 64 + lane;
      int row = c >> 2, slot = c & 3;
      int ss = slot ^ ((row >> 1) & 3);
      gld16(Ag + (size_t)row * K + ss * 8, &Ab[bidx][(w * 128 + j * 64) * 8]);
      gld16(Bg + (size_t)row * K + ss * 8, &Bb[bidx][(w * 128 + j * 64) * 8]);
    }
  };
  stage(0, 0);
  for (int kt = 0; kt < NKt; ++kt) {
    int bidx = kt & 1;
    __syncthreads();
    if (kt + 1 < NKt) stage(kt + 1, bidx ^ 1);
    bf16x8 af[4], bfv[4];
#pragma unroll
    for (int mi = 0; mi < 4; ++mi) {
      int row = wm * 64 + mi * 16 + lr;
      af[mi] = *(const bf16x8*)&Ab[bidx][row * 32 + ((sl ^ ((row >> 1) & 3)) * 8)];
    }
#pragma unroll
    for (int ni = 0; ni < 4; ++ni) {
      int row = wn * 64 + ni * 16 + lr;
      bfv[ni] = *(const bf16x8*)&Bb[bidx][row * 32 + ((sl ^ ((row >> 1) & 3)) * 8)];
    }
#pragma unroll
    for (int mi = 0; mi < 4; ++mi)
#pragma unroll
      for (int ni = 0; ni < 4; ++ni)
        acc[mi][ni] = __builtin_amdgcn_mfma_f32_16x16x32_bf16(af[mi], bfv[ni], acc[mi][ni], 0, 0, 0);
  }
#pragma unroll
  for (int ni = 0; ni < 4; ++ni) {
    int n = n0 + wn * 64 + ni * 16 + lr;
    float bv = bias[n];
#pragma unroll
    for (int mi = 0; mi < 4; ++mi) {
      int mb = m0 + wm * 64 + mi * 16 + sl * 4;
#pragma unroll
      for (int r = 0; r < 4; ++r) {
        float v = acc[mi][ni][r] + bv;
        int m = mb + r;
        if (EPI == 0) {
          int region = n >> 10, hh = (n & 1023) >> 6, d = n & 63;
          int bb = m >> 10, t = m & 1023;
          int bh = bb * NH_ + hh;
          if (region == 0)      qg[((size_t)bh * T_ + t) * HD_ + d] = (bf16)v;
          else if (region == 1) kg[((size_t)bh * T_ + t) * HD_ + d] = (bf16)v;
          else                  vtg[((size_t)bh * HD_ + d) * T_ + t] = (bf16)v;
        } else {
          outF[(size_t)m * N + n] = v;
        }
      }
    }
  }
}

// ---------- wave-paired fused attention; pinned 1-tile-deep register pipeline ----------
// Equal work per wave (heavy+light strip pair). XCD-chunked bid remap for L2 locality.
// sched_barrier(0) after each LOADKV pins load issue BEFORE the previous tile's compute.

#define LOADKV(s0v, k00, k01, k10, k11, v0, v1, v2, v3, rid0, rid1, iid0, iid1)  \
  do {                                                                           \
    int s0_ = (s0v);                                                             \
    k00 = *(const bf16x8*)(klane + (size_t)s0_ * HD_);                           \
    k01 = *(const bf16x8*)(klane + (size_t)s0_ * HD_ + 32);                      \
    k10 = *(const bf16x8*)(klane + (size_t)(s0_ + 16) * HD_);                    \
    k11 = *(const bf16x8*)(klane + (size_t)(s0_ + 16) * HD_ + 32);               \
    v0 = *(const bf16x8*)(vlane + s0_);                                          \
    v1 = *(const bf16x8*)(vlane + 16 * T_ + s0_);                                \
    v2 = *(const bf16x8*)(vlane + 32 * T_ + s0_);                                \
    v3 = *(const bf16x8*)(vlane + 48 * T_ + s0_);                                \
    rid0 = *(const u32*)(ridlane + s0_);                                         \
    rid1 = *(const u32*)(ridlane + s0_ + 16);                                    \
    iid0 = *(const u32*)(iidlane + s0_);                                         \
    iid1 = *(const u32*)(iidlane + s0_ + 16);                                    \
  } while (0)

#define COMPUTE(s0v, k00, k01, k10, k11, v0, v1, v2, v3, rid0, rid1, iid0, iid1) \
  do {                                                                           \
    int s0_ = (s0v);                                                             \
    f32x4 S0_ = {}, S1_ = {};                                                    \
    S0_ = __builtin_amdgcn_mfma_f32_16x16x32_bf16(k00, qf0, S0_, 0, 0, 0);       \
    S0_ = __builtin_amdgcn_mfma_f32_16x16x32_bf16(k01, qf1, S0_, 0, 0, 0);       \
    S1_ = __builtin_amdgcn_mfma_f32_16x16x32_bf16(k10, qf0, S1_, 0, 0, 0);       \
    S1_ = __builtin_amdgcn_mfma_f32_16x16x32_bf16(k11, qf1, S1_, 0, 0, 0);       \
    u16 pb_[8];                                                                  \
    {                                                                            \
      int sbase_ = s0_ + sl * 4;                                                 \
      _Pragma("unroll") for (int r = 0; r < 4; ++r) {                            \
        float e = (sbase_ + r <= tglob)                                          \
                      ? __expf(S0_[r] * 0.125f) * tab[(rid0 >> (8 * r)) & 63]    \
                      : 0.f;                                                     \
        lsum += e;                                                               \
        bf16 eb = (bf16)e;                                                       \
        pb_[r] = *(u16*)&eb;                                                     \
        if (e != 0.f) atomicAdd(&prel[lr * 68 + ((iid0 >> (8 * r)) & 63)], e);   \
      }                                                                          \
      sbase_ += 16;                                                              \
      _Pragma("unroll") for (int r = 0; r < 4; ++r) {                            \
        float e = (sbase_ + r <= tglob)                                          \
                      ? __expf(S1_[r] * 0.125f) * tab[(rid1 >> (8 * r)) & 63]    \
                      : 0.f;                                                     \
        lsum += e;                                                               \
        bf16 eb = (bf16)e;                                                       \
        pb_[4 + r] = *(u16*)&eb;                                                 \
        if (e != 0.f) atomicAdd(&prel[lr * 68 + ((iid1 >> (8 * r)) & 63)], e);   \
      }                                                                          \
    }                                                                            \
    u32 a0_ = (u32)pb_[0] | ((u32)pb_[1] << 16);                                 \
    u32 b0_ = (u32)pb_[2] | ((u32)pb_[3] << 16);                                 \
    u32 a1_ = (u32)pb_[4] | ((u32)pb_[5] << 16);                                 \
    u32 b1_ = (u32)pb_[6] | ((u32)pb_[7] << 16);                                 \
    int srcA_ = lr + (((sl & 1) * 2) << 4);                                      \
    int srcB_ = srcA_ + 16;                                                      \
    u32 taA0_ = (u32)__shfl((int)a0_, srcA_), taA1_ = (u32)__shfl((int)a1_, srcA_); \
    u32 tbA0_ = (u32)__shfl((int)b0_, srcA_), tbA1_ = (u32)__shfl((int)b1_, srcA_); \
    u32 taB0_ = (u32)__shfl((int)a0_, srcB_), taB1_ = (u32)__shfl((int)a1_, srcB_); \
    u32 tbB0_ = (u32)__shfl((int)b0_, srcB_), tbB1_ = (u32)__shfl((int)b1_, srcB_); \
    bool hi_ = (sl & 2) != 0;                                                    \
    u32x4 wv_;                                                                   \
    wv_[0] = hi_ ? taA1_ : taA0_;                                                \
    wv_[1] = hi_ ? tbA1_ : tbA0_;                                                \
    wv_[2] = hi_ ? taB1_ : taB0_;                                                \
    wv_[3] = hi_ ? tbB1_ : tbB0_;                                                \
    bf16x8 pfrag_ = *(bf16x8*)&wv_;                                              \
    acc[0] = __builtin_amdgcn_mfma_f32_16x16x32_bf16(v0, pfrag_, acc[0], 0, 0, 0); \
    acc[1] = __builtin_amdgcn_mfma_f32_16x16x32_bf16(v1, pfrag_, acc[1], 0, 0, 0); \
    acc[2] = __builtin_amdgcn_mfma_f32_16x16x32_bf16(v2, pfrag_, acc[2], 0, 0, 0); \
    acc[3] = __builtin_amdgcn_mfma_f32_16x16x32_bf16(v3, pfrag_, acc[3], 0, 0, 0); \
  } while (0)

__global__ __launch_bounds__(256, 2) void k_attn(
    const bf16* __restrict__ qg, const bf16* __restrict__ kg, const bf16* __restrict__ vtg,
    const u8* __restrict__ rel8, const float* __restrict__ rel_weights,
    const u8* __restrict__ relid8, const bf16* __restrict__ rvT,
    bf16* __restrict__ ret) {
  __shared__ float prelBase[4 * 1088];   // per-wave [16t][64+4pad]
  __shared__ float tabBase[4 * 64];      // per-wave exp(rel_weights[:,h])

  // XCD-chunked decode: xcd = bid&7 (round-robin assumption, perf-only).
  int bid = blockIdx.x;
  int x = bid & 7, j = bid >> 3;
  int b = x >> 1;
  int h = (x & 1) + ((j >> 3) << 1);
  int q = j & 7;
  int w = threadIdx.x >> 6;
  int lane = threadIdx.x & 63;
  int lr = lane & 15, sl = lane >> 4;
  int p = q * 4 + w;                     // pair index in [0,32)
  int bh = b * NH_ + h;

  float* prel = prelBase + w * 1088;
  float* tab = tabBase + w * 64;
  tab[lane] = __expf(rel_weights[lane * NH_ + h]);

  const u8* relbase = rel8 + (size_t)b * T_ * T_;

#pragma unroll
  for (int side = 0; side < 2; ++side) {
    int tt = side ? p : 63 - p;          // heavy strip first
    int t0 = tt * 16;
    int tglob = t0 + lr;

#pragma unroll
    for (int i = 0; i < 17; ++i) prel[i * 64 + lane] = 0.f;

    const bf16* qrow = qg + ((size_t)bh * T_ + t0 + lr) * HD_;
    bf16x8 qf0 = *(const bf16x8*)(qrow + sl * 8);
    bf16x8 qf1 = *(const bf16x8*)(qrow + 32 + sl * 8);

    const bf16* klane = kg + ((size_t)bh * T_ + lr) * HD_ + sl * 8;
    const bf16* vlane = vtg + ((size_t)bh * HD_ + lr) * T_ + sl * 8;
    const u8* ridlane = relbase + (size_t)(t0 + lr) * T_ + sl * 4;
    const u8* iidlane = relid8 + (size_t)(t0 + lr) * T_ + sl * 4;

    f32x4 acc[4] = {};
    float lsum = 0.f;

    bf16x8 ak00, ak01, ak10, ak11, av0, av1, av2, av3;
    u32 arid0, arid1, aiid0, aiid1;
    bf16x8 bk00, bk01, bk10, bk11, bv0, bv1, bv2, bv3;
    u32 brid0, brid1, biid0, biid1;

    int nst = (tt >> 1) + 1;
    LOADKV(0, ak00, ak01, ak10, ak11, av0, av1, av2, av3, arid0, arid1, aiid0, aiid1);
    __builtin_amdgcn_sched_barrier(0);
    for (int st = 0; st < nst; st += 2) {
      if (st + 1 < nst)
        LOADKV((st + 1) * 32, bk00, bk01, bk10, bk11, bv0, bv1, bv2, bv3, brid0, brid1, biid0, biid1);
      __builtin_amdgcn_sched_barrier(0);   // pin: next-tile loads issue before this tile's compute
      COMPUTE(st * 32, ak00, ak01, ak10, ak11, av0, av1, av2, av3, arid0, arid1, aiid0, aiid1);
      if (st + 1 < nst) {
        if (st + 2 < nst)
          LOADKV((st + 2) * 32, ak00, ak01, ak10, ak11, av0, av1, av2, av3, arid0, arid1, aiid0, aiid1);
        __builtin_amdgcn_sched_barrier(0);
        COMPUTE((st + 1) * 32, bk00, bk01, bk10, bk11, bv0, bv1, bv2, bv3, brid0, brid1, biid0, biid1);
      }
    }

    // ---- per-strip epilogue ----
    float v = lsum;
    v += __shfl_xor(v, 16);
    v += __shfl_xor(v, 32);
    float inv = 1.f / v;

    asm volatile("s_waitcnt lgkmcnt(0)" ::: "memory");
    __builtin_amdgcn_sched_barrier(0);
#pragma unroll
    for (int kc = 0; kc < 2; ++kc) {
      f32x4 pA = *(const f32x4*)&prel[lr * 68 + kc * 32 + sl * 8];
      f32x4 pB = *(const f32x4*)&prel[lr * 68 + kc * 32 + sl * 8 + 4];
      u16 pb[8];
#pragma unroll
      for (int jj = 0; jj < 4; ++jj) { bf16 xx = (bf16)pA[jj]; pb[jj] = *(u16*)&xx; }
#pragma unroll
      for (int jj = 0; jj < 4; ++jj) { bf16 xx = (bf16)pB[jj]; pb[4 + jj] = *(u16*)&xx; }
      bf16x8 pfrag = *(bf16x8*)&pb[0];
#pragma unroll
      for (int ni = 0; ni < 4; ++ni) {
        bf16x8 af = *(const bf16x8*)(rvT + (size_t)(ni * 16 + lr) * 64 + kc * 32 + sl * 8);
        acc[ni] = __builtin_amdgcn_mfma_f32_16x16x32_bf16(af, pfrag, acc[ni], 0, 0, 0);
      }
    }

    bf16* rp = ret + ((size_t)(b * T_ + t0 + lr)) * NX_ + h * HD_ + sl * 4;
#pragma unroll
    for (int ni = 0; ni < 4; ++ni) {
      ushort4v ov;
#pragma unroll
      for (int r = 0; r < 4; ++r) {
        bf16 xx = (bf16)(acc[ni][r] * inv);
        ov[r] = *(u16*)&xx;
      }
      *(ushort4v*)(rp + ni * 16) = ov;
    }
    asm volatile("s_waitcnt lgkmcnt(0)" ::: "memory");
  }
}

extern "C" void kernel_launch(void* const* d_in, const int* in_sizes, int n_in,
                              void* d_out, int out_size, void* d_ws, size_t ws_size,
                              hipStream_t stream) {
  const float* x = (const float*)d_in[0];
  const int* rel = (const int*)d_in[1];
  const float* w_attn = (const float*)d_in[2];
  const float* b_attn = (const float*)d_in[3];
  const float* w_proj = (const float*)d_in[4];
  const float* b_proj = (const float*)d_in[5];
  const float* rel_weights = (const float*)d_in[6];
  const float* rel_values = (const float*)d_in[7];
  const int* rel_ids = (const int*)d_in[8];
  float* out = (float*)d_out;

  char* ws = (char*)d_ws;
  bf16* xb  = (bf16*)(ws);                    //  8 MB: x as bf16 (consumed by gemm<0>)
  bf16* wTa = (bf16*)(ws + 8388608);          //  6 MB: w_attn^T
  bf16* wTp = (bf16*)(ws + 14680064);         //  2 MB: w_proj^T
  bf16* qg  = (bf16*)(ws + 16777216);         //  8 MB: q (bh,t,d)
  bf16* kg  = (bf16*)(ws + 25165824);         //  8 MB: k (bh,t,d)
  bf16* vtg = (bf16*)(ws + 33554432);         //  8 MB: v^T (bh,d,t)
  bf16* ret = (bf16*)(ws + 41943040);         //  8 MB: attn out (b,t,nx)
  // overlays on dead xb region (after gemm<0> consumed it):
  u8* rel8   = (u8*)(ws);                     //  4 MB: rel ids u8 [b][t][s]
  u8* relid8 = (u8*)(ws + 4194304);           //  1 MB: rel_ids u8 [t][s]
  bf16* rvT  = (bf16*)(ws + 5242880);         //  8 KB: rel_values^T bf16 (64d x 64rr)

  k_cvt<<<4096, 256, 0, stream>>>(x, xb, 4194304);
  k_transpose<<<dim3(48, 16), 256, 0, stream>>>(w_attn, wTa, 1024, 3072);
  k_transpose<<<dim3(16, 16), 256, 0, stream>>>(w_proj, wTp, 1024, 1024);
  k_gemm<0><<<dim3(24, 32), 256, 0, stream>>>(xb, wTa, b_attn, nullptr, qg, kg, vtg, 4096, 3072, 1024);
  k_pack<<<5120, 256, 0, stream>>>(rel, rel_ids, rel8);
  k_rvt<<<1, 256, 0, stream>>>(rel_values, rvT);
  k_attn<<<512, 256, 0, stream>>>(qg, kg, vtg, rel8, rel_weights, relid8, rvT, ret);
  k_gemm<1><<<dim3(8, 32), 256, 0, stream>>>(ret, wTp, b_proj, out, nullptr, nullptr, nullptr, 4096, 1024, 1024);
}

// Round 16
// 272.653 us; speedup vs baseline: 1.3705x; 1.0026x over previous
//
#include <hip/hip_runtime.h>
#include <hip/hip_bf16.h>

typedef __bf16 bf16;
typedef __bf16 bf16x8 __attribute__((ext_vector_type(8)));
typedef float f32x4 __attribute__((ext_vector_type(4)));
typedef unsigned char u8;
typedef unsigned int u32;
typedef unsigned short u16;
typedef u16 ushort4v __attribute__((ext_vector_type(4)));
typedef u32 u32x4 __attribute__((ext_vector_type(4)));

#define B_ 4
#define T_ 1024
#define NX_ 1024
#define NH_ 16
#define HD_ 64

__device__ __forceinline__ void gld16(const void* g, void* l) {
  __builtin_amdgcn_global_load_lds((const __attribute__((address_space(1))) void*)g,
                                   (__attribute__((address_space(3))) void*)l, 16, 0, 0);
}

// ---------- prep: contiguous fp32 -> bf16 ----------
__global__ __launch_bounds__(256) void k_cvt(const float* __restrict__ in, bf16* __restrict__ out, int n) {
  int i = (blockIdx.x * 256 + threadIdx.x) * 4;
  if (i + 3 < n) {
    float4 v = *(const float4*)(in + i);
    out[i] = (bf16)v.x; out[i + 1] = (bf16)v.y; out[i + 2] = (bf16)v.z; out[i + 3] = (bf16)v.w;
  }
}

// ---------- prep: (K,N) f32 -> (N,K) bf16 transpose ----------
__global__ __launch_bounds__(256) void k_transpose(const float* __restrict__ in, bf16* __restrict__ out, int K, int N) {
  __shared__ float tile[64][65];
  int n0 = blockIdx.x * 64, k0 = blockIdx.y * 64;
  for (int i = threadIdx.x; i < 4096; i += 256) {
    int r = i >> 6, c = i & 63;
    tile[r][c] = in[(size_t)(k0 + r) * N + n0 + c];
  }
  __syncthreads();
  for (int i = threadIdx.x; i < 4096; i += 256) {
    int r = i >> 6, c = i & 63;
    out[(size_t)(n0 + r) * K + k0 + c] = (bf16)tile[c][r];
  }
}

// ---------- pack int32 ids -> u8 ([t][s] natural layout; rel 4MB then rel_ids 1MB) ----------
__global__ __launch_bounds__(256) void k_pack(const int* __restrict__ rel, const int* __restrict__ rel_ids,
                                              u8* __restrict__ dst8) {
  int i = (blockIdx.x * 256 + threadIdx.x) * 4;
  const int* src = (i < 4194304) ? (rel + i) : (rel_ids + (i - 4194304));
  int4 v = *(const int4*)src;
  uchar4 o = {(u8)v.x, (u8)v.y, (u8)v.z, (u8)v.w};
  *(uchar4*)(dst8 + i) = o;
}

// ---------- rel_values^T as bf16 (64d x 64rr) for epilogue MFMA ----------
__global__ __launch_bounds__(256) void k_rvt(const float* __restrict__ rel_values, bf16* __restrict__ rvT) {
  int d = threadIdx.x >> 2, seg = threadIdx.x & 3;
  for (int i = 0; i < 16; ++i) {
    int rr = seg * 16 + i;
    rvT[d * 64 + rr] = (bf16)rel_values[rr * 64 + d];
  }
}

// ---------- 128x128 bf16 MFMA GEMM, BK=32, double-buffered global_load_lds ----------
template <int EPI>
__global__ __launch_bounds__(256) void k_gemm(
    const bf16* __restrict__ A, const bf16* __restrict__ BT, const float* __restrict__ bias,
    float* __restrict__ outF, bf16* __restrict__ qg, bf16* __restrict__ kg, bf16* __restrict__ vtg,
    int M, int N, int K) {
  __shared__ __align__(16) bf16 Ab[2][128 * 32];
  __shared__ __align__(16) bf16 Bb[2][128 * 32];
  int tid = threadIdx.x, lane = tid & 63, w = tid >> 6;
  int wm = w >> 1, wn = w & 1;
  int m0 = blockIdx.y * 128, n0 = blockIdx.x * 128;
  int sl = lane >> 4, lr = lane & 15;
  f32x4 acc[4][4] = {};
  int NKt = K >> 5;

  auto stage = [&](int kt, int bidx) {
    const bf16* Ag = A + (size_t)m0 * K + kt * 32;
    const bf16* Bg = BT + (size_t)n0 * K + kt * 32;
#pragma unroll
    for (int j = 0; j < 2; ++j) {
      int c = w * 128 + j * 64 + lane;
      int row = c >> 2, slot = c & 3;
      int ss = slot ^ ((row >> 1) & 3);
      gld16(Ag + (size_t)row * K + ss * 8, &Ab[bidx][(w * 128 + j * 64) * 8]);
      gld16(Bg + (size_t)row * K + ss * 8, &Bb[bidx][(w * 128 + j * 64) * 8]);
    }
  };
  stage(0, 0);
  for (int kt = 0; kt < NKt; ++kt) {
    int bidx = kt & 1;
    __syncthreads();
    if (kt + 1 < NKt) stage(kt + 1, bidx ^ 1);
    bf16x8 af[4], bfv[4];
#pragma unroll
    for (int mi = 0; mi < 4; ++mi) {
      int row = wm * 64 + mi * 16 + lr;
      af[mi] = *(const bf16x8*)&Ab[bidx][row * 32 + ((sl ^ ((row >> 1) & 3)) * 8)];
    }
#pragma unroll
    for (int ni = 0; ni < 4; ++ni) {
      int row = wn * 64 + ni * 16 + lr;
      bfv[ni] = *(const bf16x8*)&Bb[bidx][row * 32 + ((sl ^ ((row >> 1) & 3)) * 8)];
    }
#pragma unroll
    for (int mi = 0; mi < 4; ++mi)
#pragma unroll
      for (int ni = 0; ni < 4; ++ni)
        acc[mi][ni] = __builtin_amdgcn_mfma_f32_16x16x32_bf16(af[mi], bfv[ni], acc[mi][ni], 0, 0, 0);
  }
#pragma unroll
  for (int ni = 0; ni < 4; ++ni) {
    int n = n0 + wn * 64 + ni * 16 + lr;
    float bv = bias[n];
#pragma unroll
    for (int mi = 0; mi < 4; ++mi) {
      int mb = m0 + wm * 64 + mi * 16 + sl * 4;
#pragma unroll
      for (int r = 0; r < 4; ++r) {
        float v = acc[mi][ni][r] + bv;
        int m = mb + r;
        if (EPI == 0) {
          int region = n >> 10, hh = (n & 1023) >> 6, d = n & 63;
          int bb = m >> 10, t = m & 1023;
          int bh = bb * NH_ + hh;
          if (region == 0)      qg[((size_t)bh * T_ + t) * HD_ + d] = (bf16)v;
          else if (region == 1) kg[((size_t)bh * T_ + t) * HD_ + d] = (bf16)v;
          else                  vtg[((size_t)bh * HD_ + d) * T_ + t] = (bf16)v;
        } else {
          outF[(size_t)m * N + n] = v;
        }
      }
    }
  }
}

// ---------- wave-paired fused attention; hand-scheduled asm load pipeline ----------
// All global loads in the K-loop are inline-asm; ONE counted s_waitcnt vmcnt(12) per tile
// (12 next-tile loads stay in flight across the current tile's compute). rule-18 fences.

#define GLD4(dst, ptr) asm volatile("global_load_dwordx4 %0, %1, off" : "=v"(dst) : "v"(ptr))
#define GLD1(dst, ptr) asm volatile("global_load_dword %0, %1, off" : "=v"(dst) : "v"(ptr))

#define LOADKV(s0v, k00, k01, k10, k11, v0, v1, v2, v3, rid0, rid1, iid0, iid1)  \
  do {                                                                           \
    int s0_ = (s0v);                                                             \
    GLD4(k00, klane + (size_t)s0_ * HD_);                                        \
    GLD4(k01, klane + (size_t)s0_ * HD_ + 32);                                   \
    GLD4(k10, klane + (size_t)(s0_ + 16) * HD_);                                 \
    GLD4(k11, klane + (size_t)(s0_ + 16) * HD_ + 32);                            \
    GLD4(v0, vlane + s0_);                                                       \
    GLD4(v1, vlane + 16 * T_ + s0_);                                             \
    GLD4(v2, vlane + 32 * T_ + s0_);                                             \
    GLD4(v3, vlane + 48 * T_ + s0_);                                             \
    GLD1(rid0, ridlane + s0_);                                                   \
    GLD1(rid1, ridlane + s0_ + 16);                                              \
    GLD1(iid0, iidlane + s0_);                                                   \
    GLD1(iid1, iidlane + s0_ + 16);                                              \
  } while (0)

#define COMPUTE(s0v, k00, k01, k10, k11, v0, v1, v2, v3, rid0, rid1, iid0, iid1) \
  do {                                                                           \
    int s0_ = (s0v);                                                             \
    bf16x8 qf0_ = __builtin_bit_cast(bf16x8, qr0);                               \
    bf16x8 qf1_ = __builtin_bit_cast(bf16x8, qr1);                               \
    f32x4 S0_ = {}, S1_ = {};                                                    \
    S0_ = __builtin_amdgcn_mfma_f32_16x16x32_bf16(__builtin_bit_cast(bf16x8, k00), qf0_, S0_, 0, 0, 0); \
    S0_ = __builtin_amdgcn_mfma_f32_16x16x32_bf16(__builtin_bit_cast(bf16x8, k01), qf1_, S0_, 0, 0, 0); \
    S1_ = __builtin_amdgcn_mfma_f32_16x16x32_bf16(__builtin_bit_cast(bf16x8, k10), qf0_, S1_, 0, 0, 0); \
    S1_ = __builtin_amdgcn_mfma_f32_16x16x32_bf16(__builtin_bit_cast(bf16x8, k11), qf1_, S1_, 0, 0, 0); \
    u16 pb_[8];                                                                  \
    {                                                                            \
      int sbase_ = s0_ + sl * 4;                                                 \
      _Pragma("unroll") for (int r = 0; r < 4; ++r) {                            \
        float e = (sbase_ + r <= tglob)                                          \
                      ? __expf(S0_[r] * 0.125f) * tab[(rid0 >> (8 * r)) & 63]    \
                      : 0.f;                                                     \
        lsum += e;                                                               \
        bf16 eb = (bf16)e;                                                       \
        pb_[r] = *(u16*)&eb;                                                     \
        if (e != 0.f) atomicAdd(&prel[lr * 68 + ((iid0 >> (8 * r)) & 63)], e);   \
      }                                                                          \
      sbase_ += 16;                                                              \
      _Pragma("unroll") for (int r = 0; r < 4; ++r) {                            \
        float e = (sbase_ + r <= tglob)                                          \
                      ? __expf(S1_[r] * 0.125f) * tab[(rid1 >> (8 * r)) & 63]    \
                      : 0.f;                                                     \
        lsum += e;                                                               \
        bf16 eb = (bf16)e;                                                       \
        pb_[4 + r] = *(u16*)&eb;                                                 \
        if (e != 0.f) atomicAdd(&prel[lr * 68 + ((iid1 >> (8 * r)) & 63)], e);   \
      }                                                                          \
    }                                                                            \
    u32 a0_ = (u32)pb_[0] | ((u32)pb_[1] << 16);                                 \
    u32 b0_ = (u32)pb_[2] | ((u32)pb_[3] << 16);                                 \
    u32 a1_ = (u32)pb_[4] | ((u32)pb_[5] << 16);                                 \
    u32 b1_ = (u32)pb_[6] | ((u32)pb_[7] << 16);                                 \
    int srcA_ = lr + (((sl & 1) * 2) << 4);                                      \
    int srcB_ = srcA_ + 16;                                                      \
    u32 taA0_ = (u32)__shfl((int)a0_, srcA_), taA1_ = (u32)__shfl((int)a1_, srcA_); \
    u32 tbA0_ = (u32)__shfl((int)b0_, srcA_), tbA1_ = (u32)__shfl((int)b1_, srcA_); \
    u32 taB0_ = (u32)__shfl((int)a0_, srcB_), taB1_ = (u32)__shfl((int)a1_, srcB_); \
    u32 tbB0_ = (u32)__shfl((int)b0_, srcB_), tbB1_ = (u32)__shfl((int)b1_, srcB_); \
    bool hi_ = (sl & 2) != 0;                                                    \
    u32x4 wv_;                                                                   \
    wv_[0] = hi_ ? taA1_ : taA0_;                                                \
    wv_[1] = hi_ ? tbA1_ : tbA0_;                                                \
    wv_[2] = hi_ ? taB1_ : taB0_;                                                \
    wv_[3] = hi_ ? tbB1_ : tbB0_;                                                \
    bf16x8 pfrag_ = __builtin_bit_cast(bf16x8, wv_);                             \
    acc[0] = __builtin_amdgcn_mfma_f32_16x16x32_bf16(__builtin_bit_cast(bf16x8, v0), pfrag_, acc[0], 0, 0, 0); \
    acc[1] = __builtin_amdgcn_mfma_f32_16x16x32_bf16(__builtin_bit_cast(bf16x8, v1), pfrag_, acc[1], 0, 0, 0); \
    acc[2] = __builtin_amdgcn_mfma_f32_16x16x32_bf16(__builtin_bit_cast(bf16x8, v2), pfrag_, acc[2], 0, 0, 0); \
    acc[3] = __builtin_amdgcn_mfma_f32_16x16x32_bf16(__builtin_bit_cast(bf16x8, v3), pfrag_, acc[3], 0, 0, 0); \
  } while (0)

#define WAIT12() do { asm volatile("s_waitcnt vmcnt(12)" ::: "memory"); __builtin_amdgcn_sched_barrier(0); } while (0)
#define WAIT0()  do { asm volatile("s_waitcnt vmcnt(0)"  ::: "memory"); __builtin_amdgcn_sched_barrier(0); } while (0)

__global__ __launch_bounds__(256, 2) void k_attn(
    const bf16* __restrict__ qg, const bf16* __restrict__ kg, const bf16* __restrict__ vtg,
    const u8* __restrict__ rel8, const float* __restrict__ rel_weights,
    const u8* __restrict__ relid8, const bf16* __restrict__ rvT,
    bf16* __restrict__ ret) {
  __shared__ float prelBase[4 * 1088];   // per-wave [16t][64+4pad]
  __shared__ float tabBase[4 * 64];      // per-wave exp(rel_weights[:,h])

  int bid = blockIdx.x;
  int x = bid & 7, j = bid >> 3;
  int b = x >> 1;
  int h = (x & 1) + ((j >> 3) << 1);
  int q = j & 7;
  int w = threadIdx.x >> 6;
  int lane = threadIdx.x & 63;
  int lr = lane & 15, sl = lane >> 4;
  int p = q * 4 + w;                     // pair index in [0,32)
  int bh = b * NH_ + h;

  float* prel = prelBase + w * 1088;
  float* tab = tabBase + w * 64;
  tab[lane] = __expf(rel_weights[lane * NH_ + h]);

  const u8* relbase = rel8 + (size_t)b * T_ * T_;

#pragma unroll
  for (int side = 0; side < 2; ++side) {
    int tt = side ? p : 63 - p;          // heavy strip first
    int t0 = tt * 16;
    int tglob = t0 + lr;

#pragma unroll
    for (int i = 0; i < 17; ++i) prel[i * 64 + lane] = 0.f;

    const bf16* qrow = qg + ((size_t)bh * T_ + t0 + lr) * HD_;
    const bf16* klane = kg + ((size_t)bh * T_ + lr) * HD_ + sl * 8;
    const bf16* vlane = vtg + ((size_t)bh * HD_ + lr) * T_ + sl * 8;
    const u8* ridlane = relbase + (size_t)(t0 + lr) * T_ + sl * 4;
    const u8* iidlane = relid8 + (size_t)(t0 + lr) * T_ + sl * 4;

    f32x4 acc[4] = {};
    float lsum = 0.f;

    u32x4 qr0, qr1;
    GLD4(qr0, qrow + sl * 8);
    GLD4(qr1, qrow + 32 + sl * 8);

    u32x4 ak00, ak01, ak10, ak11, av0, av1, av2, av3;
    u32 arid0, arid1, aiid0, aiid1;
    u32x4 bk00, bk01, bk10, bk11, bv0, bv1, bv2, bv3;
    u32 brid0, brid1, biid0, biid1;

    int nst = (tt >> 1) + 1;
    LOADKV(0, ak00, ak01, ak10, ak11, av0, av1, av2, av3, arid0, arid1, aiid0, aiid1);
    for (int st = 0; st < nst; st += 2) {
      if (st + 1 < nst) {
        LOADKV((st + 1) * 32, bk00, bk01, bk10, bk11, bv0, bv1, bv2, bv3, brid0, brid1, biid0, biid1);
        WAIT12();
      } else {
        WAIT0();
      }
      COMPUTE(st * 32, ak00, ak01, ak10, ak11, av0, av1, av2, av3, arid0, arid1, aiid0, aiid1);
      if (st + 1 < nst) {
        if (st + 2 < nst) {
          LOADKV((st + 2) * 32, ak00, ak01, ak10, ak11, av0, av1, av2, av3, arid0, arid1, aiid0, aiid1);
          WAIT12();
        } else {
          WAIT0();
        }
        COMPUTE((st + 1) * 32, bk00, bk01, bk10, bk11, bv0, bv1, bv2, bv3, brid0, brid1, biid0, biid1);
      }
    }

    // ---- per-strip epilogue ----
    float v = lsum;
    v += __shfl_xor(v, 16);
    v += __shfl_xor(v, 32);
    float inv = 1.f / v;

    asm volatile("s_waitcnt lgkmcnt(0)" ::: "memory");
    __builtin_amdgcn_sched_barrier(0);
#pragma unroll
    for (int kc = 0; kc < 2; ++kc) {
      f32x4 pA = *(const f32x4*)&prel[lr * 68 + kc * 32 + sl * 8];
      f32x4 pB = *(const f32x4*)&prel[lr * 68 + kc * 32 + sl * 8 + 4];
      u16 pb[8];
#pragma unroll
      for (int jj = 0; jj < 4; ++jj) { bf16 xx = (bf16)pA[jj]; pb[jj] = *(u16*)&xx; }
#pragma unroll
      for (int jj = 0; jj < 4; ++jj) { bf16 xx = (bf16)pB[jj]; pb[4 + jj] = *(u16*)&xx; }
      bf16x8 pfrag = *(bf16x8*)&pb[0];
#pragma unroll
      for (int ni = 0; ni < 4; ++ni) {
        bf16x8 af = *(const bf16x8*)(rvT + (size_t)(ni * 16 + lr) * 64 + kc * 32 + sl * 8);
        acc[ni] = __builtin_amdgcn_mfma_f32_16x16x32_bf16(af, pfrag, acc[ni], 0, 0, 0);
      }
    }

    bf16* rp = ret + ((size_t)(b * T_ + t0 + lr)) * NX_ + h * HD_ + sl * 4;
#pragma unroll
    for (int ni = 0; ni < 4; ++ni) {
      ushort4v ov;
#pragma unroll
      for (int r = 0; r < 4; ++r) {
        bf16 xx = (bf16)(acc[ni][r] * inv);
        ov[r] = *(u16*)&xx;
      }
      *(ushort4v*)(rp + ni * 16) = ov;
    }
    asm volatile("s_waitcnt lgkmcnt(0)" ::: "memory");
  }
}

extern "C" void kernel_launch(void* const* d_in, const int* in_sizes, int n_in,
                              void* d_out, int out_size, void* d_ws, size_t ws_size,
                              hipStream_t stream) {
  const float* x = (const float*)d_in[0];
  const int* rel = (const int*)d_in[1];
  const float* w_attn = (const float*)d_in[2];
  const float* b_attn = (const float*)d_in[3];
  const float* w_proj = (const float*)d_in[4];
  const float* b_proj = (const float*)d_in[5];
  const float* rel_weights = (const float*)d_in[6];
  const float* rel_values = (const float*)d_in[7];
  const int* rel_ids = (const int*)d_in[8];
  float* out = (float*)d_out;

  char* ws = (char*)d_ws;
  bf16* xb  = (bf16*)(ws);                    //  8 MB: x as bf16 (consumed by gemm<0>)
  bf16* wTa = (bf16*)(ws + 8388608);          //  6 MB: w_attn^T
  bf16* wTp = (bf16*)(ws + 14680064);         //  2 MB: w_proj^T
  bf16* qg  = (bf16*)(ws + 16777216);         //  8 MB: q (bh,t,d)
  bf16* kg  = (bf16*)(ws + 25165824);         //  8 MB: k (bh,t,d)
  bf16* vtg = (bf16*)(ws + 33554432);         //  8 MB: v^T (bh,d,t)
  bf16* ret = (bf16*)(ws + 41943040);         //  8 MB: attn out (b,t,nx)
  // overlays on dead xb region (after gemm<0> consumed it):
  u8* rel8   = (u8*)(ws);                     //  4 MB: rel ids u8 [b][t][s]
  u8* relid8 = (u8*)(ws + 4194304);           //  1 MB: rel_ids u8 [t][s]
  bf16* rvT  = (bf16*)(ws + 5242880);         //  8 KB: rel_values^T bf16 (64d x 64rr)

  k_cvt<<<4096, 256, 0, stream>>>(x, xb, 4194304);
  k_transpose<<<dim3(48, 16), 256, 0, stream>>>(w_attn, wTa, 1024, 3072);
  k_transpose<<<dim3(16, 16), 256, 0, stream>>>(w_proj, wTp, 1024, 1024);
  k_gemm<0><<<dim3(24, 32), 256, 0, stream>>>(xb, wTa, b_attn, nullptr, qg, kg, vtg, 4096, 3072, 1024);
  k_pack<<<5120, 256, 0, stream>>>(rel, rel_ids, rel8);
  k_rvt<<<1, 256, 0, stream>>>(rel_values, rvT);
  k_attn<<<512, 256, 0, stream>>>(qg, kg, vtg, rel8, rel_weights, relid8, rvT, ret);
  k_gemm<1><<<dim3(8, 32), 256, 0, stream>>>(ret, wTp, b_proj, out, nullptr, nullptr, nullptr, 4096, 1024, 1024);
}